// Round 7
// baseline (807.353 us; speedup 1.0000x reference)
//
#include <hip/hip_runtime.h>

#define N_NODES 16384
#define KDIM    16384
#define E_EDGES 524288
#define H1DIM   200
#define H2DIM   8
#define BNP     256     // padded H1

#define BM 64
#define BK 32
#define KSPLIT 4
#define KLEN 4096       // KDIM / KSPLIT
#define NT 128          // KLEN / BK

typedef __attribute__((ext_vector_type(8))) short bf16x8;
typedef __attribute__((ext_vector_type(4))) float fx4;
typedef __attribute__((ext_vector_type(4))) unsigned int ux4;
typedef __attribute__((ext_vector_type(2))) unsigned int ux2;

__device__ __forceinline__ unsigned short f2bf(float f) {
  unsigned int u = __builtin_bit_cast(unsigned int, f);
  return (unsigned short)((u + 0x7FFFu + ((u >> 16) & 1u)) >> 16);  // RNE
}
__device__ __forceinline__ unsigned int pk2(float a, float b) {
  return (unsigned int)f2bf(a) | ((unsigned int)f2bf(b) << 16);
}
__device__ __forceinline__ float bf2f(unsigned int u) {
  return __builtin_bit_cast(float, u << 16);
}

// ---------------- degree / CSR build ----------------

__global__ void k_degcnt(const int* __restrict__ ei, const float* __restrict__ ew,
                         float* deg, int* cnt) {
  int e = blockIdx.x * 256 + threadIdx.x;
  if (e < E_EDGES) {
    int c = ei[E_EDGES + e];
    atomicAdd(&deg[c], ew[e]);
    atomicAdd(&cnt[c], 1);
  }
}

// scan over cnt -> off/cursor; also computes dinv = rsqrt(deg) (fused, deg ready)
__global__ void k_scan(const int* __restrict__ cnt, int* __restrict__ off,
                       int* __restrict__ cursor, const float* __restrict__ deg,
                       float* __restrict__ dinv) {
  __shared__ int s[1024];
  int t = threadIdx.x;
  int base = t * 16;
#pragma unroll
  for (int i = 0; i < 16; ++i) dinv[base + i] = rsqrtf(deg[base + i]);
  int loc[16]; int sum = 0;
#pragma unroll
  for (int i = 0; i < 16; ++i) { loc[i] = cnt[base + i]; sum += loc[i]; }
  s[t] = sum; __syncthreads();
  for (int d = 1; d < 1024; d <<= 1) {
    int v = (t >= d) ? s[t - d] : 0;
    __syncthreads();
    s[t] += v;
    __syncthreads();
  }
  int run = (t == 0) ? 0 : s[t - 1];
#pragma unroll
  for (int i = 0; i < 16; ++i) { off[base + i] = run; cursor[base + i] = run; run += loc[i]; }
  if (t == 1023) off[N_NODES] = run;
}

__global__ void k_scatter(const int* __restrict__ ei, const float* __restrict__ ew,
                          const float* __restrict__ dinv, int* cursor,
                          int* __restrict__ r2, float* __restrict__ w2) {
  int e = blockIdx.x * 256 + threadIdx.x;
  if (e < E_EDGES) {
    int r = ei[e], c = ei[E_EDGES + e];
    float w = dinv[r] * ew[e] * dinv[c];
    int p = atomicAdd(&cursor[c], 1);
    r2[p] = r; w2[p] = w;
  }
}

// ---------------- W1 pack (bf16, pad to 256, [k/8][n][8]) + deg/cnt init fused ----------------

__global__ void k_packW1(const float* __restrict__ W1, unsigned short* __restrict__ Wt,
                         float* deg, int* cnt) {
  int idx = blockIdx.x * 256 + threadIdx.x;   // < 16384*256
  if (idx < N_NODES) { deg[idx] = 1.0f; cnt[idx] = 0; }   // self-loop weight 1.0
  int n = idx & 255, k = idx >> 8;
  float v = (n < H1DIM) ? W1[(size_t)k * H1DIM + n] : 0.0f;
  Wt[(size_t)(k >> 3) * 2048 + n * 8 + (k & 7)] = f2bf(v);
}

// ---------------- GEMM1: h1p[ks] = x[:, kslice] @ W1pad  (bf16 MFMA) ----------------
// R5 structure verbatim (best: 505 us). THIS ROUND: launched TWICE to measure
// t_gemm1 by subtraction (new_dur - 505).

#define LOADA(KT, AI)                                   \
  { const float* _p = xp0 + (KT) * BK;                  \
    aR[AI][0] = *(const fx4*)_p;                        \
    aR[AI][1] = *(const fx4*)(_p + 4); }

#define STAGEB(BUF, KT)                                                                  \
  { const unsigned short* _s = wbase + (size_t)(KT) * 8192 + (size_t)t * 8;              \
    char* _d = ldsB + (BUF) * 16384 + wv * 1024;                                         \
    __builtin_amdgcn_global_load_lds((const __attribute__((address_space(1))) void*)(_s),                      (__attribute__((address_space(3))) void*)(_d),         16, 0, 0); \
    __builtin_amdgcn_global_load_lds((const __attribute__((address_space(1))) void*)(((const char*)_s)+4096),  (__attribute__((address_space(3))) void*)(_d+4096),    16, 0, 0); \
    __builtin_amdgcn_global_load_lds((const __attribute__((address_space(1))) void*)(((const char*)_s)+8192),  (__attribute__((address_space(3))) void*)(_d+8192),    16, 0, 0); \
    __builtin_amdgcn_global_load_lds((const __attribute__((address_space(1))) void*)(((const char*)_s)+12288), (__attribute__((address_space(3))) void*)(_d+12288),   16, 0, 0); }

#define WRITEA(AI)                                          \
  { ux4 _dv;                                                \
    _dv[0] = pk2(aR[AI][0][0], aR[AI][0][1]);               \
    _dv[1] = pk2(aR[AI][0][2], aR[AI][0][3]);               \
    _dv[2] = pk2(aR[AI][1][0], aR[AI][1][1]);               \
    _dv[3] = pk2(aR[AI][1][2], aR[AI][1][3]);               \
    *(ux4*)(ldsA + (AI) * 4096 + ((akblk * 64 + am) << 4)) = _dv; }

#define COMPUTE(BUF)                                                                     \
  { const char* _pa = ldsA + (BUF) * 4096;                                               \
    const char* _pb = ldsB + (BUF) * 16384;                                              \
    bf16x8 _af[4], _bf[4];                                                               \
    _Pragma("unroll")                                                                    \
    for (int mi = 0; mi < 4; ++mi)                                                       \
      _af[mi] = *(const bf16x8*)(_pa + ((g * 64 + mi * 16 + l15) << 4));                 \
    _Pragma("unroll")                                                                    \
    for (int ni = 0; ni < 4; ++ni)                                                       \
      _bf[ni] = *(const bf16x8*)(_pb + ((g * 256 + wv * 64 + ni * 16 + l15) << 4));      \
    _Pragma("unroll")                                                                    \
    for (int mi = 0; mi < 4; ++mi)                                                       \
      _Pragma("unroll")                                                                  \
      for (int ni = 0; ni < 4; ++ni)                                                     \
        acc[mi][ni] = __builtin_amdgcn_mfma_f32_16x16x32_bf16(_af[mi], _bf[ni], acc[mi][ni], 0, 0, 0); }

#define SYNC_VM(N)                                          \
  __builtin_amdgcn_sched_barrier(0);                        \
  asm volatile("s_waitcnt vmcnt(" #N ")" ::: "memory");     \
  asm volatile("s_waitcnt lgkmcnt(0)" ::: "memory");        \
  __builtin_amdgcn_s_barrier();                             \
  __builtin_amdgcn_sched_barrier(0);

#define GSTEP(KT, PAR)                 \
  STAGEB((PAR) ^ 1, (KT) + 1)          \
  __builtin_amdgcn_sched_barrier(0);   \
  LOADA((KT) + 2, PAR)                 \
  __builtin_amdgcn_sched_barrier(0);   \
  COMPUTE(PAR)                         \
  WRITEA((PAR) ^ 1)                    \
  SYNC_VM(2)

__launch_bounds__(256, 4)
__global__ void k_gemm1(const float* __restrict__ x, const unsigned short* __restrict__ Wt,
                        float* __restrict__ h1p) {
  __shared__ char lds[40960];       // A: [2][4096] @0, B: [2][16384] @8192
  const int t = threadIdx.x;
  const int wv = t >> 6;
  const int ln = t & 63;
  const int g = ln >> 4, l15 = ln & 15;
  const int bid = blockIdx.x;
  const int ks = bid & 3;
  const size_t m0 = (size_t)(bid >> 2) * BM;
  const int k0 = ks * KLEN;

  const int am = t >> 2;
  const int akblk = t & 3;
  const float* xp0 = x + (m0 + am) * (size_t)KDIM + k0 + akblk * 8;
  const unsigned short* wbase = Wt + (size_t)k0 * 256;

  char* ldsA = lds;
  char* ldsB = lds + 8192;

  fx4 acc[4][4] = {};
  fx4 aR[2][2];

  // prologue: A(0),A(1) -> regs; B(0) staged; A(0) -> LDS; drain.
  LOADA(0, 0)
  LOADA(1, 1)
  STAGEB(0, 0)
  WRITEA(0)
  SYNC_VM(0)

  // steady: steps 0..125 (NT-2 = 126, unroll by 2 for literal parity)
  for (int kt = 0; kt < NT - 2; kt += 2) {
    GSTEP(kt + 0, 0)
    GSTEP(kt + 1, 1)
  }

  // step 126 (par 0): stage last B, no A load, full drain.
  STAGEB(1, NT - 1)
  __builtin_amdgcn_sched_barrier(0);
  COMPUTE(0)
  WRITEA(1)
  SYNC_VM(0)
  // step 127 (par 1)
  COMPUTE(1)

  float* outp = h1p + (size_t)ks * ((size_t)N_NODES * BNP);
#pragma unroll
  for (int mi = 0; mi < 4; ++mi)
#pragma unroll
    for (int ni = 0; ni < 4; ++ni)
#pragma unroll
      for (int r = 0; r < 4; ++r)
        outp[(m0 + mi * 16 + g * 4 + r) * BNP + wv * 64 + ni * 16 + l15] = acc[mi][ni][r];
}

// ---------------- reduce K-split partials -> compact bf16 h1 [16384][200] ----------------

__global__ void k_reduce(const float* __restrict__ h1p, unsigned short* __restrict__ h1b) {
  size_t i = (size_t)blockIdx.x * 256 + threadIdx.x;   // < 1048576 fx4 units of padded grid
  int cb = (int)(i & 63);            // column block (4 cols each)
  if (cb < 50) {                     // cols 200..255 are zero padding: skip entirely
    const fx4* a = (const fx4*)h1p;
    fx4 v = a[i];
    v += a[i + 1048576]; v += a[i + 2097152]; v += a[i + 3145728];
    size_t row = i >> 6;
    ux2 o;
    o[0] = pk2(v[0], v[1]);
    o[1] = pk2(v[2], v[3]);
    *(ux2*)(h1b + row * H1DIM + cb * 4) = o;
  }
}

// ---------------- layer-1 aggregation + bias + relu ----------------

__global__ void k_agg1(const unsigned short* __restrict__ h1b, const int* __restrict__ r2,
                       const float* __restrict__ w2, const int* __restrict__ off,
                       const float* __restrict__ dinv, const float* __restrict__ b1,
                       float* __restrict__ h1r) {
  int c = blockIdx.x;
  int j = threadIdx.x;          // active: j < 200
  if (j >= H1DIM) return;
  int p0 = off[c], p1 = off[c + 1];
  float acc = 0.0f;
  int p = p0;
  for (; p + 4 <= p1; p += 4) {       // 4-way unroll: break the serial latency chain
    int ra = r2[p], rb = r2[p + 1], rc = r2[p + 2], rd = r2[p + 3];
    float wa = w2[p], wb = w2[p + 1], wc = w2[p + 2], wd = w2[p + 3];
    float va = bf2f((unsigned int)h1b[(size_t)ra * H1DIM + j]);
    float vb = bf2f((unsigned int)h1b[(size_t)rb * H1DIM + j]);
    float vc = bf2f((unsigned int)h1b[(size_t)rc * H1DIM + j]);
    float vd = bf2f((unsigned int)h1b[(size_t)rd * H1DIM + j]);
    acc += wa * va + wb * vb + wc * vc + wd * vd;
  }
  for (; p < p1; ++p)
    acc += w2[p] * bf2f((unsigned int)h1b[(size_t)r2[p] * H1DIM + j]);
  float d = dinv[c];
  acc += d * d * bf2f((unsigned int)h1b[(size_t)c * H1DIM + j]);
  acc += b1[j];
  h1r[(size_t)c * H1DIM + j] = fmaxf(acc, 0.0f);
}

// ---------------- layer-2 linear ----------------

__global__ void k_gemm2(const float* __restrict__ h1r, const float* __restrict__ W2,
                        float* __restrict__ g) {
  __shared__ float w2s[H1DIM * H2DIM];
  int t = threadIdx.x;
  for (int i = t; i < H1DIM * H2DIM; i += 256) w2s[i] = W2[i];
  __syncthreads();
  int r = t >> 3, j = t & 7;
  size_t i = (size_t)blockIdx.x * 32 + r;
  const float* hrow = h1r + i * H1DIM;
  float acc = 0.0f;
#pragma unroll 8
  for (int k = 0; k < H1DIM; ++k) acc = fmaf(hrow[k], w2s[k * 8 + j], acc);
  g[i * 8 + j] = acc;
}

// ---------------- layer-2 aggregation + bias ----------------

__global__ void k_agg2(const float* __restrict__ g, const int* __restrict__ r2,
                       const float* __restrict__ w2, const int* __restrict__ off,
                       const float* __restrict__ dinv, const float* __restrict__ b2,
                       float* __restrict__ out) {
  int t = threadIdx.x;
  int c = blockIdx.x * 32 + (t >> 3), j = t & 7;
  int p0 = off[c], p1 = off[c + 1];
  float acc = 0.0f;
  for (int p = p0; p < p1; ++p) acc += w2[p] * g[(size_t)r2[p] * 8 + j];
  float d = dinv[c];
  out[(size_t)c * 8 + j] = acc + d * d * g[(size_t)c * 8 + j] + b2[j];
}

// ---------------- launch ----------------

extern "C" void kernel_launch(void* const* d_in, const int* in_sizes, int n_in,
                              void* d_out, int out_size, void* d_ws, size_t ws_size,
                              hipStream_t stream) {
  (void)in_sizes; (void)n_in; (void)out_size; (void)ws_size;
  const float* x  = (const float*)d_in[0];
  const int*   ei = (const int*)d_in[1];
  const float* ew = (const float*)d_in[2];
  const float* W1 = (const float*)d_in[3];
  const float* b1 = (const float*)d_in[4];
  const float* W2 = (const float*)d_in[5];
  const float* b2 = (const float*)d_in[6];
  float* out = (float*)d_out;
  char* ws = (char*)d_ws;

  float* deg    = (float*)(ws + 0);          // 64 KiB
  float* dinv   = (float*)(ws + 65536);      // 64 KiB
  int*   cnt    = (int*)  (ws + 131072);     // 64 KiB
  int*   off    = (int*)  (ws + 196608);     // 16385 ints
  int*   cursor = (int*)  (ws + 262400);     // 64 KiB
  int*   r2     = (int*)  (ws + 327936);     // 2 MiB
  float* w2     = (float*)(ws + 2425088);    // 2 MiB
  unsigned short* Wt = (unsigned short*)(ws + 4522240);   // 8 MiB bf16 packed
  float* h1p    = (float*)(ws + 12910848);   // 4 * [16384][256] f32 = 64 MiB
  float* h1r    = (float*)(ws + 80019712);   // [16384][200] f32
  float* g      = (float*)(ws + 93126912);   // [16384][8] f32
  unsigned short* h1b = (unsigned short*)(ws + 93651200); // [16384][200] bf16 = 6.55 MiB

  k_packW1 <<<16384, 256, 0, stream>>>(W1, Wt, deg, cnt);
  k_degcnt <<<2048,  256, 0, stream>>>(ei, ew, deg, cnt);
  k_scan   <<<1,    1024, 0, stream>>>(cnt, off, cursor, deg, dinv);
  k_scatter<<<2048,  256, 0, stream>>>(ei, ew, dinv, cursor, r2, w2);
  // MEASUREMENT: gemm1 launched twice (identical output, deterministic).
  // t_gemm1 = dur_us(this round) - dur_us(R5 = 505.2 us).
  k_gemm1  <<<1024,  256, 0, stream>>>(x, Wt, h1p);
  k_gemm1  <<<1024,  256, 0, stream>>>(x, Wt, h1p);
  k_reduce <<<4096,  256, 0, stream>>>(h1p, h1b);
  k_agg1   <<<16384, 256, 0, stream>>>(h1b, r2, w2, off, dinv, b1, h1r);
  k_gemm2  <<<512,   256, 0, stream>>>(h1r, W2, g);
  k_agg2   <<<512,   256, 0, stream>>>(g, r2, w2, off, dinv, b2, out);
}

// Round 10
// 431.620 us; speedup vs baseline: 1.8705x; 1.8705x over previous
//
#include <hip/hip_runtime.h>

#define N_NODES 16384
#define KDIM    16384
#define E_EDGES 524288
#define H1DIM   200
#define H2DIM   8
#define BNP     256     // padded H1

#define BM 128
#define BK 32
#define KSPLIT 4
#define KLEN 4096       // KDIM / KSPLIT
#define NT 128          // KLEN / BK

typedef __attribute__((ext_vector_type(8))) short bf16x8;
typedef __attribute__((ext_vector_type(4))) float fx4;
typedef __attribute__((ext_vector_type(4))) unsigned int ux4;
typedef __attribute__((ext_vector_type(2))) unsigned int ux2;

__device__ __forceinline__ unsigned short f2bf(float f) {
  unsigned int u = __builtin_bit_cast(unsigned int, f);
  return (unsigned short)((u + 0x7FFFu + ((u >> 16) & 1u)) >> 16);  // RNE
}
__device__ __forceinline__ unsigned int pk2(float a, float b) {
  return (unsigned int)f2bf(a) | ((unsigned int)f2bf(b) << 16);
}
__device__ __forceinline__ float bf2f(unsigned int u) {
  return __builtin_bit_cast(float, u << 16);
}

// ---------------- degree / CSR build (R5 verbatim) ----------------

__global__ void k_degcnt(const int* __restrict__ ei, const float* __restrict__ ew,
                         float* deg, int* cnt) {
  int e = blockIdx.x * 256 + threadIdx.x;
  if (e < E_EDGES) {
    int c = ei[E_EDGES + e];
    atomicAdd(&deg[c], ew[e]);
    atomicAdd(&cnt[c], 1);
  }
}

__global__ void k_scan(const int* __restrict__ cnt, int* __restrict__ off,
                       int* __restrict__ cursor, const float* __restrict__ deg,
                       float* __restrict__ dinv) {
  __shared__ int s[1024];
  int t = threadIdx.x;
  int base = t * 16;
#pragma unroll
  for (int i = 0; i < 16; ++i) dinv[base + i] = rsqrtf(deg[base + i]);
  int loc[16]; int sum = 0;
#pragma unroll
  for (int i = 0; i < 16; ++i) { loc[i] = cnt[base + i]; sum += loc[i]; }
  s[t] = sum; __syncthreads();
  for (int d = 1; d < 1024; d <<= 1) {
    int v = (t >= d) ? s[t - d] : 0;
    __syncthreads();
    s[t] += v;
    __syncthreads();
  }
  int run = (t == 0) ? 0 : s[t - 1];
#pragma unroll
  for (int i = 0; i < 16; ++i) { off[base + i] = run; cursor[base + i] = run; run += loc[i]; }
  if (t == 1023) off[N_NODES] = run;
}

__global__ void k_scatter(const int* __restrict__ ei, const float* __restrict__ ew,
                          const float* __restrict__ dinv, int* cursor,
                          int* __restrict__ r2, float* __restrict__ w2) {
  int e = blockIdx.x * 256 + threadIdx.x;
  if (e < E_EDGES) {
    int r = ei[e], c = ei[E_EDGES + e];
    float w = dinv[r] * ew[e] * dinv[c];
    int p = atomicAdd(&cursor[c], 1);
    r2[p] = r; w2[p] = w;
  }
}

// ---------------- W1 pack (R5 verbatim: bf16, pad to 256, [k/8][n][8]) ----------------

__global__ void k_packW1(const float* __restrict__ W1, unsigned short* __restrict__ Wt,
                         float* deg, int* cnt) {
  int idx = blockIdx.x * 256 + threadIdx.x;   // < 16384*256
  if (idx < N_NODES) { deg[idx] = 1.0f; cnt[idx] = 0; }   // self-loop weight 1.0
  int n = idx & 255, k = idx >> 8;
  float v = (n < H1DIM) ? W1[(size_t)k * H1DIM + n] : 0.0f;
  Wt[(size_t)(k >> 3) * 2048 + n * 8 + (k & 7)] = f2bf(v);
}

// ---------------- GEMM1: h1p[ks] = x[:, kslice] @ W1pad  (bf16 MFMA) ----------------
// ONLY change vs the 505-us R5 baseline: BM=128, 512 threads (8 waves, 2x4 grid),
// 512 blocks -> halves B-from-L2 vmem traffic (R7-measured choke). ks=bid&3 XCD-pure.
// Counted-vmcnt schedule preserved: steady queue [A(k+1):2, B(k+1):2, A(k+2):2],
// implicit vmcnt(4) at WRITEA, SYNC_VM(2).

#define LOADA(KT, AI)                                   \
  { const float* _p = xp0 + (KT) * BK;                  \
    aR[AI][0] = *(const fx4*)_p;                        \
    aR[AI][1] = *(const fx4*)(_p + 4); }

#define STAGEB(BUF, KT)                                                                  \
  { const unsigned short* _s = wbase + (size_t)(KT) * 8192 + (size_t)t * 8;              \
    char* _d = ldsB + (BUF) * 16384 + wv * 1024;                                         \
    __builtin_amdgcn_global_load_lds((const __attribute__((address_space(1))) void*)(_s),        (__attribute__((address_space(3))) void*)(_d),        16, 0, 0); \
    __builtin_amdgcn_global_load_lds((const __attribute__((address_space(1))) void*)(_s + 4096), (__attribute__((address_space(3))) void*)(_d + 8192), 16, 0, 0); }

#define WRITEA(AI)                                          \
  { ux4 _dv;                                                \
    _dv[0] = pk2(aR[AI][0][0], aR[AI][0][1]);               \
    _dv[1] = pk2(aR[AI][0][2], aR[AI][0][3]);               \
    _dv[2] = pk2(aR[AI][1][0], aR[AI][1][1]);               \
    _dv[3] = pk2(aR[AI][1][2], aR[AI][1][3]);               \
    *(ux4*)(ldsA + (AI) * 8192 + ((akblk * 128 + am) << 4)) = _dv; }

#define COMPUTE(BUF)                                                                     \
  { const char* _pa = ldsA + (BUF) * 8192;                                               \
    const char* _pb = ldsB + (BUF) * 16384;                                              \
    bf16x8 _af[4], _bf[4];                                                               \
    _Pragma("unroll")                                                                    \
    for (int mi = 0; mi < 4; ++mi)                                                       \
      _af[mi] = *(const bf16x8*)(_pa + ((g * 128 + wm * 64 + mi * 16 + l15) << 4));      \
    _Pragma("unroll")                                                                    \
    for (int ni = 0; ni < 4; ++ni)                                                       \
      _bf[ni] = *(const bf16x8*)(_pb + ((g * 256 + wn * 64 + ni * 16 + l15) << 4));      \
    _Pragma("unroll")                                                                    \
    for (int mi = 0; mi < 4; ++mi)                                                       \
      _Pragma("unroll")                                                                  \
      for (int ni = 0; ni < 4; ++ni)                                                     \
        acc[mi][ni] = __builtin_amdgcn_mfma_f32_16x16x32_bf16(_af[mi], _bf[ni], acc[mi][ni], 0, 0, 0); }

#define SYNC_VM(N)                                          \
  __builtin_amdgcn_sched_barrier(0);                        \
  asm volatile("s_waitcnt vmcnt(" #N ")" ::: "memory");     \
  asm volatile("s_waitcnt lgkmcnt(0)" ::: "memory");        \
  __builtin_amdgcn_s_barrier();                             \
  __builtin_amdgcn_sched_barrier(0);

#define GSTEP(KT, PAR)                 \
  STAGEB((PAR) ^ 1, (KT) + 1)          \
  __builtin_amdgcn_sched_barrier(0);   \
  LOADA((KT) + 2, PAR)                 \
  __builtin_amdgcn_sched_barrier(0);   \
  COMPUTE(PAR)                         \
  WRITEA((PAR) ^ 1)                    \
  SYNC_VM(2)

__launch_bounds__(512, 4)
__global__ void k_gemm1(const float* __restrict__ x, const unsigned short* __restrict__ Wt,
                        float* __restrict__ h1p) {
  __shared__ char lds[49152];       // A: [2][8192] @0, B: [2][16384] @16384
  const int t = threadIdx.x;
  const int wv = t >> 6;
  const int wm = wv >> 2, wn = wv & 3;
  const int ln = t & 63;
  const int g = ln >> 4, l15 = ln & 15;
  const int bid = blockIdx.x;
  const int ks = bid & 3;
  const size_t m0 = (size_t)(bid >> 2) * BM;
  const int k0 = ks * KLEN;

  // A staging coords: thread t -> (row = t/4 [0..127], kblk = t%4)
  const int am = t >> 2;
  const int akblk = t & 3;
  const float* xp0 = x + (m0 + am) * (size_t)KDIM + k0 + akblk * 8;
  const unsigned short* wbase = Wt + (size_t)k0 * 256;

  char* ldsA = lds;
  char* ldsB = lds + 16384;

  fx4 acc[4][4] = {};
  fx4 aR[2][2];

  // prologue: A(0),A(1) -> regs; B(0) staged; A(0) -> LDS; drain.
  LOADA(0, 0)
  LOADA(1, 1)
  STAGEB(0, 0)
  WRITEA(0)
  SYNC_VM(0)

  // steady: steps 0..125 (NT-2 = 126, unroll by 2 for literal parity)
  for (int kt = 0; kt < NT - 2; kt += 2) {
    GSTEP(kt + 0, 0)
    GSTEP(kt + 1, 1)
  }

  // step 126 (par 0): stage last B, no A load, drains.
  STAGEB(1, NT - 1)
  __builtin_amdgcn_sched_barrier(0);
  COMPUTE(0)
  WRITEA(1)
  SYNC_VM(0)
  // step 127 (par 1)
  COMPUTE(1)

  float* outp = h1p + (size_t)ks * ((size_t)N_NODES * BNP);
#pragma unroll
  for (int mi = 0; mi < 4; ++mi)
#pragma unroll
    for (int ni = 0; ni < 4; ++ni)
#pragma unroll
      for (int r = 0; r < 4; ++r)
        outp[(m0 + wm * 64 + mi * 16 + g * 4 + r) * BNP + wn * 64 + ni * 16 + l15] = acc[mi][ni][r];
}

// ---------------- reduce K-split partials -> compact bf16 h1 [16384][200] (R5 verbatim) ----------------

__global__ void k_reduce(const float* __restrict__ h1p, unsigned short* __restrict__ h1b) {
  size_t i = (size_t)blockIdx.x * 256 + threadIdx.x;   // < 1048576 fx4 units of padded grid
  int cb = (int)(i & 63);            // column block (4 cols each)
  if (cb < 50) {                     // cols 200..255 are zero padding: skip entirely
    const fx4* a = (const fx4*)h1p;
    fx4 v = a[i];
    v += a[i + 1048576]; v += a[i + 2097152]; v += a[i + 3145728];
    size_t row = i >> 6;
    ux2 o;
    o[0] = pk2(v[0], v[1]);
    o[1] = pk2(v[2], v[3]);
    *(ux2*)(h1b + row * H1DIM + cb * 4) = o;
  }
}

// ---------------- layer-1 aggregation + bias + relu (R5 verbatim) ----------------

__global__ void k_agg1(const unsigned short* __restrict__ h1b, const int* __restrict__ r2,
                       const float* __restrict__ w2, const int* __restrict__ off,
                       const float* __restrict__ dinv, const float* __restrict__ b1,
                       float* __restrict__ h1r) {
  int c = blockIdx.x;
  int j = threadIdx.x;          // active: j < 200
  if (j >= H1DIM) return;
  int p0 = off[c], p1 = off[c + 1];
  float acc = 0.0f;
  int p = p0;
  for (; p + 4 <= p1; p += 4) {       // 4-way unroll: break the serial latency chain
    int ra = r2[p], rb = r2[p + 1], rc = r2[p + 2], rd = r2[p + 3];
    float wa = w2[p], wb = w2[p + 1], wc = w2[p + 2], wd = w2[p + 3];
    float va = bf2f((unsigned int)h1b[(size_t)ra * H1DIM + j]);
    float vb = bf2f((unsigned int)h1b[(size_t)rb * H1DIM + j]);
    float vc = bf2f((unsigned int)h1b[(size_t)rc * H1DIM + j]);
    float vd = bf2f((unsigned int)h1b[(size_t)rd * H1DIM + j]);
    acc += wa * va + wb * vb + wc * vc + wd * vd;
  }
  for (; p < p1; ++p)
    acc += w2[p] * bf2f((unsigned int)h1b[(size_t)r2[p] * H1DIM + j]);
  float d = dinv[c];
  acc += d * d * bf2f((unsigned int)h1b[(size_t)c * H1DIM + j]);
  acc += b1[j];
  h1r[(size_t)c * H1DIM + j] = fmaxf(acc, 0.0f);
}

// ---------------- layer-2 linear (R5 verbatim) ----------------

__global__ void k_gemm2(const float* __restrict__ h1r, const float* __restrict__ W2,
                        float* __restrict__ g) {
  __shared__ float w2s[H1DIM * H2DIM];
  int t = threadIdx.x;
  for (int i = t; i < H1DIM * H2DIM; i += 256) w2s[i] = W2[i];
  __syncthreads();
  int r = t >> 3, j = t & 7;
  size_t i = (size_t)blockIdx.x * 32 + r;
  const float* hrow = h1r + i * H1DIM;
  float acc = 0.0f;
#pragma unroll 8
  for (int k = 0; k < H1DIM; ++k) acc = fmaf(hrow[k], w2s[k * 8 + j], acc);
  g[i * 8 + j] = acc;
}

// ---------------- layer-2 aggregation + bias (R5 verbatim) ----------------

__global__ void k_agg2(const float* __restrict__ g, const int* __restrict__ r2,
                       const float* __restrict__ w2, const int* __restrict__ off,
                       const float* __restrict__ dinv, const float* __restrict__ b2,
                       float* __restrict__ out) {
  int t = threadIdx.x;
  int c = blockIdx.x * 32 + (t >> 3), j = t & 7;
  int p0 = off[c], p1 = off[c + 1];
  float acc = 0.0f;
  for (int p = p0; p < p1; ++p) acc += w2[p] * g[(size_t)r2[p] * 8 + j];
  float d = dinv[c];
  out[(size_t)c * 8 + j] = acc + d * d * g[(size_t)c * 8 + j] + b2[j];
}

// ---------------- launch ----------------

extern "C" void kernel_launch(void* const* d_in, const int* in_sizes, int n_in,
                              void* d_out, int out_size, void* d_ws, size_t ws_size,
                              hipStream_t stream) {
  (void)in_sizes; (void)n_in; (void)out_size; (void)ws_size;
  const float* x  = (const float*)d_in[0];
  const int*   ei = (const int*)d_in[1];
  const float* ew = (const float*)d_in[2];
  const float* W1 = (const float*)d_in[3];
  const float* b1 = (const float*)d_in[4];
  const float* W2 = (const float*)d_in[5];
  const float* b2 = (const float*)d_in[6];
  float* out = (float*)d_out;
  char* ws = (char*)d_ws;

  float* deg    = (float*)(ws + 0);          // 64 KiB
  float* dinv   = (float*)(ws + 65536);      // 64 KiB
  int*   cnt    = (int*)  (ws + 131072);     // 64 KiB
  int*   off    = (int*)  (ws + 196608);     // 16385 ints
  int*   cursor = (int*)  (ws + 262400);     // 64 KiB
  int*   r2     = (int*)  (ws + 327936);     // 2 MiB
  float* w2     = (float*)(ws + 2425088);    // 2 MiB
  unsigned short* Wt = (unsigned short*)(ws + 4522240);   // 8 MiB bf16 packed
  float* h1p    = (float*)(ws + 12910848);   // 4 * [16384][256] f32 = 64 MiB
  float* h1r    = (float*)(ws + 80019712);   // [16384][200] f32
  float* g      = (float*)(ws + 93126912);   // [16384][8] f32
  unsigned short* h1b = (unsigned short*)(ws + 93651200); // [16384][200] bf16 = 6.55 MiB

  k_packW1 <<<16384, 256, 0, stream>>>(W1, Wt, deg, cnt);
  k_degcnt <<<2048,  256, 0, stream>>>(ei, ew, deg, cnt);
  k_scan   <<<1,    1024, 0, stream>>>(cnt, off, cursor, deg, dinv);
  k_scatter<<<2048,  256, 0, stream>>>(ei, ew, dinv, cursor, r2, w2);
  k_gemm1  <<<512,   512, 0, stream>>>(x, Wt, h1p);
  k_reduce <<<4096,  256, 0, stream>>>(h1p, h1b);
  k_agg1   <<<16384, 256, 0, stream>>>(h1b, r2, w2, off, dinv, b1, h1r);
  k_gemm2  <<<512,   256, 0, stream>>>(h1r, W2, g);
  k_agg2   <<<512,   256, 0, stream>>>(g, r2, w2, off, dinv, b2, out);
}